// Round 14
// baseline (125.262 us; speedup 1.0000x reference)
//
#include <hip/hip_runtime.h>
#include <stdint.h>
#include <stddef.h>

// ---------------------------------------------------------------------------
// ModuleGARO. R14 = R13 with k_gemm rebuilt on the m97-verified 128x128
// geometry: wave-tile 64x64 (4x4 frags, 32 MFMA / 32KB staged = 1.5x the
// FLOP/B of BM=64), ksplit=80 (8 k-tiles/block), single-buffered 32KB LDS,
// 2-barrier loop (cross-block overlap at ~2.5-5 blocks/CU hides staging).
// P = 80 bf16 groups (21MB). All else identical to R13 (verified 119.2us).
// R11 lesson kept: NO device-scope fences in hot kernels.
// Symmetry fold (R9): WTf[(i,j)] = W_ij+W_ji (j<i), W_ii, 0 (j>i).
// ---------------------------------------------------------------------------

typedef short short8 __attribute__((ext_vector_type(8)));
typedef float f32x4 __attribute__((ext_vector_type(4)));

#define DEV __device__ __forceinline__

DEV unsigned short f2bf(float f){
  union { float f; unsigned u; } v; v.f = f;
  unsigned r = v.u + 0x7FFFu + ((v.u >> 16) & 1u);   // RNE
  return (unsigned short)(r >> 16);
}
DEV float bf2f(unsigned short b){
  union { unsigned u; float f; } v; v.u = ((unsigned)b) << 16;
  return v.f;
}
DEV void gload_lds16(const void* g, void* l){
  __builtin_amdgcn_global_load_lds(
      (const __attribute__((address_space(1))) unsigned int*)g,
      (__attribute__((address_space(3))) unsigned int*)l, 16, 0, 0);
}

// decode triangle-tile index t (0..639) -> (i, jc)
DEV void tri_decode(int t, int& i, int& jc){
  int a, u;
  if (t < 64)       { a = 0; u = t; }
  else if (t < 192) { a = 1; u = t - 64; }
  else if (t < 384) { a = 2; u = t - 192; }
  else              { a = 3; u = t - 384; }
  int idx = (a == 0) ? u : (a == 1) ? (u >> 1) : (a == 2) ? (u / 3) : (u >> 2);
  jc = u - idx * (a + 1);
  i = 64*a + idx;
}

// ---------------------------------------------------------------------------
// k_wtf: blocks [0,2560) = folded transpose of m1W into WTf; blocks
// [2560,2640) = tail-weight transposes + SQ zero. (R13 verified, f32x4 loads)
// ---------------------------------------------------------------------------
__global__ __launch_bounds__(256) void k_wtf(const float* __restrict__ W,
                                             unsigned short* __restrict__ WTf,
                                             const float* __restrict__ m2W,
                                             const float* __restrict__ p1W,
                                             const float* __restrict__ p2W,
                                             const float* __restrict__ kW,
                                             unsigned short* __restrict__ WTs,
                                             float2* __restrict__ SQ){
  __shared__ float tile [64][65];
  __shared__ float tile2[64][65];
  const int tr = threadIdx.x >> 6, tc = threadIdx.x & 63;
  const int r0v = threadIdx.x >> 4;          // 0..15 (row base for vec loads)
  const int c4  = (threadIdx.x & 15) * 4;    // column quad
  const int bid = blockIdx.x;

  if (bid >= 2560){
    const int sub = bid - 2560;              // 0..79
    if (sub == 0){
      for (int i = threadIdx.x; i < 1024; i += 256) SQ[i] = make_float2(0.f, 0.f);
    }
    const int bx = sub >> 2, oy = sub & 3;
    const float* Ws; int K; size_t dst; int kt;
    if (bx < 4)       { Ws = m2W; K = 256; dst = 0;      kt = bx; }
    else if (bx < 12) { Ws = p1W; K = 512; dst = 65536;  kt = bx - 4; }
    else if (bx < 16) { Ws = p2W; K = 256; dst = 196608; kt = bx - 12; }
    else              { Ws = kW;  K = 256; dst = 262144; kt = bx - 16; }
    const int k0 = kt*64, o0 = oy*64;
    #pragma unroll
    for (int q = 0; q < 4; ++q){
      int kr = q*16 + r0v;
      f32x4 v = *(const f32x4*)&Ws[(size_t)(k0+kr)*256 + o0 + c4];
      tile[kr][c4]   = v[0]; tile[kr][c4+1] = v[1];
      tile[kr][c4+2] = v[2]; tile[kr][c4+3] = v[3];
    }
    __syncthreads();
    #pragma unroll
    for (int q = 0; q < 16; ++q){
      int orow = q*4 + tr;
      WTs[dst + (size_t)(o0+orow)*K + k0 + tc] = f2bf(tile[tc][orow]);
    }
    return;
  }

  int i, jc;
  tri_decode(bid >> 2, i, jc);
  const int j0 = jc * 64;
  const int o0 = (bid & 3) * 64;
  #pragma unroll
  for (int q = 0; q < 4; ++q){
    int kr = q*16 + r0v;
    f32x4 v  = *(const f32x4*)&W[(size_t)(i*256 + j0 + kr)*256 + o0 + c4];   // W[(i,j)][o]
    f32x4 v2 = *(const f32x4*)&W[(size_t)((j0 + kr)*256 + i)*256 + o0 + c4]; // W[(j,i)][o]
    tile [kr][c4]   = v[0];  tile [kr][c4+1] = v[1];
    tile [kr][c4+2] = v[2];  tile [kr][c4+3] = v[3];
    tile2[kr][c4]   = v2[0]; tile2[kr][c4+1] = v2[1];
    tile2[kr][c4+2] = v2[2]; tile2[kr][c4+3] = v2[3];
  }
  __syncthreads();
  #pragma unroll
  for (int q = 0; q < 16; ++q){
    int orow = q*4 + tr;
    int j = j0 + tc;
    float v = (j < i) ? (tile[tc][orow] + tile2[tc][orow])
            : (j == i) ? tile[tc][orow] : 0.f;
    WTf[(size_t)(o0+orow)*65536 + (size_t)i*256 + j0 + tc] = f2bf(v);
  }
}

// ---------------------------------------------------------------------------
// k_corr2: one block per bt; lower-triangle only; per-wave 16x264 LDS row
// tile for coalesced fc stores. (R10 verified)
// ---------------------------------------------------------------------------
__global__ __launch_bounds__(256) void k_corr2(const float* __restrict__ x,
                                               unsigned short* __restrict__ fc){
  __shared__ unsigned short yT[256*72];
  __shared__ float rs[256];
  __shared__ unsigned short twbuf[4][16*264];
  const int bt = blockIdx.x;
  const float* xb = x + (size_t)bt * 16384;
  const int i = threadIdx.x;

  float sum = 0.f;
  #pragma unroll 8
  for (int s = 0; s < 64; ++s) sum += xb[s*256 + i];
  const float mean = sum * (1.f/64.f);

  float ss = 0.f;
  unsigned int* yT32 = (unsigned int*)yT;
  #pragma unroll 4
  for (int s = 0; s < 64; s += 2){
    float v0 = xb[s*256 + i] - mean;
    float v1 = xb[(s+1)*256 + i] - mean;
    unsigned short b0 = f2bf(v0), b1 = f2bf(v1);
    float r0 = bf2f(b0), r1 = bf2f(b1);
    ss += r0*r0 + r1*r1;
    yT32[(i*72 + s) >> 1] = (unsigned)b0 | ((unsigned)b1 << 16);
  }
  rs[i] = rsqrtf(ss);
  __syncthreads();

  const int w   = threadIdx.x >> 6;
  const int l   = threadIdx.x & 63;
  const int l15 = l & 15, lg = l >> 4;
  const int rtiles[4] = {2*w, 2*w + 1, 14 - 2*w, 15 - 2*w};
  unsigned short* tw = twbuf[w];

  for (int q = 0; q < 4; ++q){
    const int rt = rtiles[q];
    const int band = rt >> 2;
    const int ccmax = 2*band + 1;

    short8 RF[2];
    #pragma unroll
    for (int ks = 0; ks < 2; ++ks)
      RF[ks] = *(const short8*)&yT[(rt*16 + l15)*72 + ks*32 + lg*8];
    float rrow[4];
    #pragma unroll
    for (int r = 0; r < 4; ++r) rrow[r] = rs[rt*16 + lg*4 + r];

    for (int cc = 0; cc <= ccmax; ++cc){
      short8 CF[2][2];
      #pragma unroll
      for (int ct = 0; ct < 2; ++ct){
        int col = cc*32 + ct*16 + l15;
        #pragma unroll
        for (int ks = 0; ks < 2; ++ks)
          CF[ct][ks] = *(const short8*)&yT[col*72 + ks*32 + lg*8];
      }
      f32x4 acc[2];
      #pragma unroll
      for (int ct = 0; ct < 2; ++ct) acc[ct] = (f32x4){0.f,0.f,0.f,0.f};
      #pragma unroll
      for (int ks = 0; ks < 2; ++ks)
        #pragma unroll
        for (int ct = 0; ct < 2; ++ct)
          acc[ct] = __builtin_amdgcn_mfma_f32_16x16x32_bf16(
              RF[ks], CF[ct][ks], acc[ct], 0, 0, 0);
      float rc[2] = { rs[cc*32 + l15], rs[cc*32 + 16 + l15] };
      #pragma unroll
      for (int ct = 0; ct < 2; ++ct)
        #pragma unroll
        for (int r = 0; r < 4; ++r){
          float v = acc[ct][r] * rrow[r] * rc[ct];
          v = fminf(fmaxf(v, -1.f), 1.f);
          tw[(lg*4 + r)*264 + cc*32 + ct*16 + l15] = f2bf(v);
        }
    }
    // coalesced store: 16 rows x nc cols (DS in-order per wave; no barrier)
    const int nc  = (ccmax + 1) * 32;
    const int spr = nc >> 3;               // 8-elem slots per row
    const int total = spr << 4;            // 16 rows
    for (int s = l; s < total; s += 64){
      int r  = s / spr;
      int co = (s - r*spr) * 8;
      short8 v = *(const short8*)&tw[r*264 + co];
      *(short8*)&fc[(size_t)bt*65536 + (size_t)(rt*16 + r)*256 + co] = v;
    }
  }
}

// ---------------------------------------------------------------------------
// k_gemm: triangle-folded GEMM, m97 geometry: BM=BN=128, BK=64, 4 waves
// (wave-tile 64x64, 4x4 frags), single-buffered 32KB LDS, 2-barrier loop.
// grid 640 = 80 k-groups x 8 (m,n); XCD swizzle; P partials bf16.
// ---------------------------------------------------------------------------
__global__ __launch_bounds__(256) void k_gemm(const unsigned short* __restrict__ fc,
                                              const unsigned short* __restrict__ WTf,
                                              unsigned short* __restrict__ P){
  __shared__ unsigned short Al[128*64];
  __shared__ unsigned short Bl[128*64];
  const int bid  = blockIdx.x;
  const int wgid = (bid & 7)*80 + (bid >> 3);   // bijective (640 % 8 == 0)
  const int g    = wgid >> 3;                   // 0..79
  const int cmb  = wgid & 7;
  const int n0   = (cmb >> 2) * 128;            // 0,128
  const int m0   = (cmb & 3) * 128;             // 0..384
  const int t    = threadIdx.x;
  const int w = t >> 6, l = t & 63, l15 = l & 15, lg = l >> 4;
  const int wr = (w >> 1) * 64;    // 0,64
  const int wc = (w & 1) * 64;     // 0,64

  f32x4 acc[4][4];
  #pragma unroll
  for (int a = 0; a < 4; ++a)
    #pragma unroll
    for (int b = 0; b < 4; ++b) acc[a][b] = (f32x4){0.f,0.f,0.f,0.f};

  for (int kt = 0; kt < 8; ++kt){
    int ti, tjc;
    tri_decode(g*8 + kt, ti, tjc);
    const int kk = ti*256 + tjc*64;
    #pragma unroll
    for (int i2 = 0; i2 < 4; ++i2){            // A: 128 rows x 64 k
      int c = i2*256 + t;
      int row = c >> 3, ch = c & 7;
      int sch = ch ^ (row & 7);
      gload_lds16(fc + (size_t)(m0+row)*65536 + kk + sch*8, &Al[c*8]);
    }
    #pragma unroll
    for (int i2 = 0; i2 < 4; ++i2){            // B: 128 rows x 64 k
      int c = i2*256 + t;
      int row = c >> 3, ch = c & 7;
      int sch = ch ^ (row & 7);
      gload_lds16(WTf + (size_t)(n0+row)*65536 + kk + sch*8, &Bl[c*8]);
    }
    __syncthreads();                 // drains vmcnt: tiles staged
    #pragma unroll
    for (int ks = 0; ks < 2; ++ks){
      short8 af[4], bf[4];
      #pragma unroll
      for (int rt = 0; rt < 4; ++rt){
        int row = wr + rt*16 + l15;
        int pch = (ks*4 + lg) ^ (row & 7);
        af[rt] = *(const short8*)&Al[row*64 + pch*8];
      }
      #pragma unroll
      for (int ct = 0; ct < 4; ++ct){
        int row = wc + ct*16 + l15;
        int pch = (ks*4 + lg) ^ (row & 7);
        bf[ct] = *(const short8*)&Bl[row*64 + pch*8];
      }
      #pragma unroll
      for (int rt = 0; rt < 4; ++rt)
        #pragma unroll
        for (int ct = 0; ct < 4; ++ct)
          acc[rt][ct] = __builtin_amdgcn_mfma_f32_16x16x32_bf16(
              af[rt], bf[ct], acc[rt][ct], 0, 0, 0);
    }
    __syncthreads();                 // reads done before next stage
  }

  unsigned short* Pb = P + (size_t)g * 131072;
  #pragma unroll
  for (int rt = 0; rt < 4; ++rt)
    #pragma unroll
    for (int ct = 0; ct < 4; ++ct)
      #pragma unroll
      for (int r = 0; r < 4; ++r){
        int row = m0 + wr + rt*16 + lg*4 + r;
        int col = n0 + wc + ct*16 + l15;
        Pb[(size_t)row*256 + col] = f2bf(acc[rt][ct][r]);
      }
}

// ---------------------------------------------------------------------------
// k_reduce: z1 = sum_{g<80} bf16 P[g]; fused BN1 stats partials via atomicAdd.
// ---------------------------------------------------------------------------
__global__ __launch_bounds__(256) void k_reduce(const unsigned short* __restrict__ P,
                                                float* __restrict__ z,
                                                float2* __restrict__ SQ1){
  __shared__ float4 ex[128];
  const int t = threadIdx.x;
  const int row = blockIdx.x*2 + (t >> 7);
  const int c2  = (t & 127) * 2;
  float sx = 0.f, sy = 0.f;
  #pragma unroll 8
  for (int ks = 0; ks < 80; ++ks){
    unsigned u = *(const unsigned*)&P[(size_t)ks*131072 + row*256 + c2];
    sx += bf2f((unsigned short)(u & 0xffffu));
    sy += bf2f((unsigned short)(u >> 16));
  }
  z[row*256 + c2]     = sx;
  z[row*256 + c2 + 1] = sy;
  if (t >= 128) ex[t & 127] = make_float4(sx, sx*sx, sy, sy*sy);
  __syncthreads();
  if (t < 128){
    float4 o = ex[t];
    atomicAdd(&SQ1[c2].x,     sx + o.x);
    atomicAdd(&SQ1[c2].y,     sx*sx + o.y);
    atomicAdd(&SQ1[c2 + 1].x, sy + o.z);
    atomicAdd(&SQ1[c2 + 1].y, sy*sy + o.w);
  }
}

// ---------------------------------------------------------------------------
// k_sgm: weight-stationary MFMA layer. 16 rows x 64 cols per block,
// grid (32,4) = 128 blocks. (R10 verified)
// ---------------------------------------------------------------------------
template<int KK, int NC64, bool CAT>
__global__ __launch_bounds__(256) void k_sgm(const float* __restrict__ zin,
                                             const float* __restrict__ es,
                                             const unsigned short* __restrict__ WTl_g,
                                             const float2* __restrict__ SQin,
                                             const float* __restrict__ g,
                                             const float* __restrict__ be,
                                             float2* __restrict__ SQout,
                                             float* __restrict__ zout){
  constexpr int NCOLS = NC64 * 64;
  constexpr int NP = KK / 64;
  __shared__ unsigned short Bl[NP][NCOLS*64];
  __shared__ float2 ssl[256];
  const int r0 = blockIdx.x * 16;
  const int n0 = blockIdx.y * NCOLS;
  const int b  = r0 >> 6;
  const int t = threadIdx.x;
  const int l = t & 63, l15 = l & 15, lg = (l >> 4) & 3;
  const int w = t >> 6;
  const int wc = w * (NCOLS/4);

  #pragma unroll
  for (int p = 0; p < NP; ++p){
    #pragma unroll
    for (int i = 0; i < NCOLS*8/256; ++i){
      int c = i*256 + t;
      int row = c >> 3, ch = c & 7;
      int sch = ch ^ (row & 7);
      gload_lds16(WTl_g + (size_t)(n0+row)*KK + p*64 + sch*8, &Bl[p][c*8]);
    }
  }
  {
    float2 sq = SQin[t];
    float mu  = sq.x * (1.f/512.f);
    float var = sq.y * (1.f/512.f) - mu*mu;
    float sc  = g[t] * rsqrtf(var + 1e-5f);
    ssl[t] = make_float2(sc, be[t] - mu*sc);
  }
  __syncthreads();

  short8 a[KK/32];
  #pragma unroll
  for (int ks = 0; ks < KK/32; ++ks){
    int k = ks*32 + lg*8;
    short8 v;
    if (!CAT || k < 256){
      f32x4 lo = *(const f32x4*)&zin[(size_t)(r0+l15)*256 + k];
      f32x4 hi = *(const f32x4*)&zin[(size_t)(r0+l15)*256 + k + 4];
      #pragma unroll
      for (int j = 0; j < 4; ++j){
        float2 sv0 = ssl[k+j];
        float2 sv1 = ssl[k+4+j];
        v[j]   = (short)f2bf(fmaxf(lo[j]*sv0.x + sv0.y, 0.f));
        v[4+j] = (short)f2bf(fmaxf(hi[j]*sv1.x + sv1.y, 0.f));
      }
    } else {
      f32x4 lo = *(const f32x4*)&es[b*256 + (k-256)];
      f32x4 hi = *(const f32x4*)&es[b*256 + (k-256) + 4];
      #pragma unroll
      for (int j = 0; j < 4; ++j){
        v[j]   = (short)f2bf(lo[j]);
        v[4+j] = (short)f2bf(hi[j]);
      }
    }
    a[ks] = v;
  }

  f32x4 acc[NC64];
  #pragma unroll
  for (int ct = 0; ct < NC64; ++ct) acc[ct] = (f32x4){0.f,0.f,0.f,0.f};
  #pragma unroll
  for (int ks = 0; ks < KK/32; ++ks){
    int p = ks >> 1;
    int kin = (ks & 1) * 4;
    #pragma unroll
    for (int ct = 0; ct < NC64; ++ct){
      int row = wc + ct*16 + l15;
      int pch = (kin + lg) ^ (row & 7);
      short8 bfr = *(const short8*)&Bl[p][row*64 + pch*8];
      acc[ct] = __builtin_amdgcn_mfma_f32_16x16x32_bf16(a[ks], bfr, acc[ct], 0, 0, 0);
    }
  }

  #pragma unroll
  for (int ct = 0; ct < NC64; ++ct){
    int col = n0 + wc + ct*16 + l15;
    #pragma unroll
    for (int r = 0; r < 4; ++r)
      zout[(size_t)(r0 + lg*4 + r)*256 + col] = acc[ct][r];
    float S = acc[ct][0] + acc[ct][1] + acc[ct][2] + acc[ct][3];
    float Q = acc[ct][0]*acc[ct][0] + acc[ct][1]*acc[ct][1]
            + acc[ct][2]*acc[ct][2] + acc[ct][3]*acc[ct][3];
    S += __shfl_xor(S, 16); S += __shfl_xor(S, 32);
    Q += __shfl_xor(Q, 16); Q += __shfl_xor(Q, 32);
    if ((l >> 4) == 0){
      atomicAdd(&SQout[col].x, S);
      atomicAdd(&SQout[col].y, Q);
    }
  }
}

// ---------------------------------------------------------------------------
// k_qmean2: 32 blocks = (8 b) x (4 col-quarters). (R10 verified)
// ---------------------------------------------------------------------------
__global__ __launch_bounds__(256) void k_qmean2(const float* __restrict__ z4,
                                                const float2* __restrict__ SQ4,
                                                const float* __restrict__ g,
                                                const float* __restrict__ be,
                                                const float* __restrict__ qW,
                                                const float* __restrict__ qb,
                                                float* __restrict__ q){
  __shared__ float qWl[256*64];    // 64KB: qW[:, n0..n0+64) packed [k][c]
  __shared__ float hm[256];
  __shared__ float part[4][64];
  const int b  = blockIdx.x & 7;
  const int n0 = (blockIdx.x >> 3) * 64;
  const int t  = threadIdx.x;

  #pragma unroll
  for (int it = 0; it < 16; ++it){
    int s4 = it*256 + t;           // 16B-slot index
    int k  = s4 >> 4;
    int c  = (s4 & 15) * 4;
    gload_lds16(qW + (size_t)k*256 + n0 + c, (char*)qWl + (size_t)s4*16);
  }
  {
    float2 sq = SQ4[t];
    float mu  = sq.x * (1.f/512.f);
    float var = sq.y * (1.f/512.f) - mu*mu;
    float sc  = g[t] * rsqrtf(var + 1e-5f);
    float sh  = be[t] - mu*sc;
    float s = 0.f;
    #pragma unroll 8
    for (int tt = 0; tt < 64; ++tt)
      s += fmaxf(z4[(size_t)((b<<6)+tt)*256 + t]*sc + sh, 0.f);
    hm[t] = s * (1.f/64.f);
  }
  __syncthreads();                 // drains qW gloads + hm visible

  const int col = t & 63, kq = t >> 6;
  float a = 0.f;
  #pragma unroll 8
  for (int k2 = 0; k2 < 64; ++k2){
    int k = kq*64 + k2;
    a += hm[k] * qWl[k*64 + col];
  }
  part[kq][col] = a;
  __syncthreads();
  if (t < 64)
    q[b*256 + n0 + t] = part[0][t] + part[1][t] + part[2][t] + part[3][t] + qb[n0 + t];
}

// ---------------------------------------------------------------------------
// k_att2: 16 rows/block; Hh = relu(bn4(z4)); kvec = Hh@kW + kb;
// s = dot(q_b,kvec)/16; out = Hh*sigmoid(s). (R7-R13 verified)
// ---------------------------------------------------------------------------
__global__ __launch_bounds__(256) void k_att2(const float* __restrict__ z4,
                                              const float2* __restrict__ SQ4,
                                              const float* __restrict__ g,
                                              const float* __restrict__ be,
                                              const unsigned short* __restrict__ kWT,
                                              const float* __restrict__ kb,
                                              const float* __restrict__ qv,
                                              float* __restrict__ out){
  __shared__ unsigned short Bl[4][256*64];
  __shared__ float2 ssl[256];
  __shared__ float Hh[16][260];
  __shared__ float pr[4][16];
  __shared__ float sig[16];
  const int r0 = blockIdx.x * 16;
  const int b  = r0 >> 6;
  const int t = threadIdx.x;
  const int l = t & 63, l15 = l & 15, lg = (l >> 4) & 3;
  const int w = t >> 6;
  const int wc = w * 64;

  #pragma unroll
  for (int p = 0; p < 4; ++p){
    #pragma unroll
    for (int i = 0; i < 8; ++i){
      int c = i*256 + t;
      int row = c >> 3, ch = c & 7;
      int sch = ch ^ (row & 7);
      gload_lds16(kWT + (size_t)row*256 + p*64 + sch*8, &Bl[p][c*8]);
    }
  }
  {
    float2 sq = SQ4[t];
    float mu  = sq.x * (1.f/512.f);
    float var = sq.y * (1.f/512.f) - mu*mu;
    float sc  = g[t] * rsqrtf(var + 1e-5f);
    ssl[t] = make_float2(sc, be[t] - mu*sc);
  }
  __syncthreads();

  short8 a[8];
  #pragma unroll
  for (int ks = 0; ks < 8; ++ks){
    int k = ks*32 + lg*8;
    f32x4 lo = *(const f32x4*)&z4[(size_t)(r0+l15)*256 + k];
    f32x4 hi = *(const f32x4*)&z4[(size_t)(r0+l15)*256 + k + 4];
    short8 v;
    f32x4 h0, h1;
    #pragma unroll
    for (int j = 0; j < 4; ++j){
      float2 sv0 = ssl[k+j];
      float2 sv1 = ssl[k+4+j];
      float x0 = fmaxf(lo[j]*sv0.x + sv0.y, 0.f);
      float x1 = fmaxf(hi[j]*sv1.x + sv1.y, 0.f);
      h0[j] = x0; h1[j] = x1;
      v[j]   = (short)f2bf(x0);
      v[4+j] = (short)f2bf(x1);
    }
    a[ks] = v;
    *(f32x4*)&Hh[l15][k]     = h0;
    *(f32x4*)&Hh[l15][k + 4] = h1;
  }

  f32x4 acc[4];
  #pragma unroll
  for (int ct = 0; ct < 4; ++ct) acc[ct] = (f32x4){0.f,0.f,0.f,0.f};
  #pragma unroll
  for (int ks = 0; ks < 8; ++ks){
    int p = ks >> 1;
    int kin = (ks & 1) * 4;
    #pragma unroll
    for (int ct = 0; ct < 4; ++ct){
      int row = wc + ct*16 + l15;
      int pch = (kin + lg) ^ (row & 7);
      short8 bfr = *(const short8*)&Bl[p][row*64 + pch*8];
      acc[ct] = __builtin_amdgcn_mfma_f32_16x16x32_bf16(a[ks], bfr, acc[ct], 0, 0, 0);
    }
  }

  float p4[4] = {0.f, 0.f, 0.f, 0.f};
  #pragma unroll
  for (int ct = 0; ct < 4; ++ct){
    int col = wc + ct*16 + l15;
    float qc  = qv[b*256 + col];
    float kbc = kb[col];
    #pragma unroll
    for (int r = 0; r < 4; ++r) p4[r] += (acc[ct][r] + kbc) * qc;
  }
  #pragma unroll
  for (int r = 0; r < 4; ++r){
    p4[r] += __shfl_xor(p4[r], 1);
    p4[r] += __shfl_xor(p4[r], 2);
    p4[r] += __shfl_xor(p4[r], 4);
    p4[r] += __shfl_xor(p4[r], 8);
  }
  if (l15 == 0){
    #pragma unroll
    for (int r = 0; r < 4; ++r) pr[w][lg*4 + r] = p4[r];
  }
  __syncthreads();
  if (t < 16){
    float s = pr[0][t] + pr[1][t] + pr[2][t] + pr[3][t];
    sig[t] = 1.f / (1.f + __expf(-s * (1.f/16.f)));
  }
  __syncthreads();
  #pragma unroll
  for (int r = 0; r < 16; ++r)
    out[(size_t)(r0+r)*256 + t] = Hh[r][t] * sig[r];
}

// ---------------------------------------------------------------------------
extern "C" void kernel_launch(void* const* d_in, const int* in_sizes, int n_in,
                              void* d_out, int out_size, void* d_ws, size_t ws_size,
                              hipStream_t stream){
  (void)in_sizes; (void)n_in; (void)out_size; (void)ws_size;
  const float* x    = (const float*)d_in[0];
  const float* e_s  = (const float*)d_in[1];
  const float* qW   = (const float*)d_in[2];
  const float* qb   = (const float*)d_in[3];
  const float* kW   = (const float*)d_in[4];
  const float* kb   = (const float*)d_in[5];
  const float* m1W  = (const float*)d_in[6];
  const float* m1g  = (const float*)d_in[8];
  const float* m1be = (const float*)d_in[9];
  const float* m2W  = (const float*)d_in[10];
  const float* m2g  = (const float*)d_in[12];
  const float* m2be = (const float*)d_in[13];
  const float* p1W  = (const float*)d_in[14];
  const float* p1g  = (const float*)d_in[16];
  const float* p1be = (const float*)d_in[17];
  const float* p2W  = (const float*)d_in[18];
  const float* p2g  = (const float*)d_in[20];
  const float* p2be = (const float*)d_in[21];
  // biases m1b,m2b,p1b,p2b cancel in BN — unused.

  char* ws = (char*)d_ws;
  unsigned short* WTf = (unsigned short*)ws; ws += 33554432;
  unsigned short* fc  = (unsigned short*)ws; ws += 67108864;
  unsigned short* P   = (unsigned short*)ws; ws += 20971520;  // 80 bf16 groups (21MB)
  float* z1           = (float*)ws;  ws += 524288;
  float* z2           = (float*)ws;  ws += 524288;
  float* z3           = (float*)ws;  ws += 524288;
  float* z4           = (float*)ws;  ws += 524288;
  unsigned short* WTs = (unsigned short*)ws; ws += 655360;
  float2* SQ          = (float2*)ws; ws += 8192;   // SQ1..SQ4, 256 each
  float* qvv          = (float*)ws;  ws += 8192;
  float* out = (float*)d_out;

  const unsigned short* m2WT = WTs;
  const unsigned short* p1WT = WTs + 65536;
  const unsigned short* p2WT = WTs + 196608;
  const unsigned short* kWT  = WTs + 262144;
  float2* SQ1 = SQ, *SQ2 = SQ + 256, *SQ3 = SQ + 512, *SQ4 = SQ + 768;

  k_wtf   <<<2640, 256, 0, stream>>>(m1W, WTf, m2W, p1W, p2W, kW, WTs, SQ);
  k_corr2 <<<512, 256, 0, stream>>>(x, fc);
  k_gemm  <<<640, 256, 0, stream>>>(fc, WTf, P);
  k_reduce<<<256, 256, 0, stream>>>(P, z1, SQ1);
  k_sgm<256,1,false><<<dim3(32,4), 256, 0, stream>>>(z1, nullptr, m2WT, SQ1, m1g, m1be, SQ2, z2);
  k_sgm<512,1,true> <<<dim3(32,4), 256, 0, stream>>>(z2, e_s, p1WT, SQ2, m2g, m2be, SQ3, z3);
  k_sgm<256,1,false><<<dim3(32,4), 256, 0, stream>>>(z3, nullptr, p2WT, SQ3, p1g, p1be, SQ4, z4);
  k_qmean2<<<32, 256, 0, stream>>>(z4, SQ4, p2g, p2be, qW, qb, qvv);
  k_att2  <<<32, 256, 0, stream>>>(z4, SQ4, p2g, p2be, kWT, kb, qvv, out);
}

// Round 15
// 100.948 us; speedup vs baseline: 1.2409x; 1.2409x over previous
//
#include <hip/hip_runtime.h>
#include <stdint.h>
#include <stddef.h>

// ---------------------------------------------------------------------------
// ModuleGARO. R15 = R13 (verified 119.2us, best) + vectorized k_reduce
// (8B loads, 128 blocks x 4 rows, f32x4 z-store, LDS cross-wave stats).
// R14 lesson: BM64/BN128 2-phase-dbuf ksplit40 gemm is the local optimum
// (128^2 single-buf ksplit80 = +6us). R11 lesson: NO device-scope fences.
// Symmetry fold (R9): WTf[(i,j)] = W_ij+W_ji (j<i), W_ii, 0 (j>i); GEMM runs
// 640 of 1024 k-tiles. Linear biases cancel in BN.
// ---------------------------------------------------------------------------

typedef short short8 __attribute__((ext_vector_type(8)));
typedef float f32x4 __attribute__((ext_vector_type(4)));

#define DEV __device__ __forceinline__

DEV unsigned short f2bf(float f){
  union { float f; unsigned u; } v; v.f = f;
  unsigned r = v.u + 0x7FFFu + ((v.u >> 16) & 1u);   // RNE
  return (unsigned short)(r >> 16);
}
DEV float bf2f(unsigned short b){
  union { unsigned u; float f; } v; v.u = ((unsigned)b) << 16;
  return v.f;
}
DEV void gload_lds16(const void* g, void* l){
  __builtin_amdgcn_global_load_lds(
      (const __attribute__((address_space(1))) unsigned int*)g,
      (__attribute__((address_space(3))) unsigned int*)l, 16, 0, 0);
}

// decode triangle-tile index t (0..639) -> (i, jc)
DEV void tri_decode(int t, int& i, int& jc){
  int a, u;
  if (t < 64)       { a = 0; u = t; }
  else if (t < 192) { a = 1; u = t - 64; }
  else if (t < 384) { a = 2; u = t - 192; }
  else              { a = 3; u = t - 384; }
  int idx = (a == 0) ? u : (a == 1) ? (u >> 1) : (a == 2) ? (u / 3) : (u >> 2);
  jc = u - idx * (a + 1);
  i = 64*a + idx;
}

// ---------------------------------------------------------------------------
// k_wtf: blocks [0,2560) = folded transpose of m1W into WTf; blocks
// [2560,2640) = tail-weight transposes + SQ zero. (R13 verified, f32x4 loads)
// ---------------------------------------------------------------------------
__global__ __launch_bounds__(256) void k_wtf(const float* __restrict__ W,
                                             unsigned short* __restrict__ WTf,
                                             const float* __restrict__ m2W,
                                             const float* __restrict__ p1W,
                                             const float* __restrict__ p2W,
                                             const float* __restrict__ kW,
                                             unsigned short* __restrict__ WTs,
                                             float2* __restrict__ SQ){
  __shared__ float tile [64][65];
  __shared__ float tile2[64][65];
  const int tr = threadIdx.x >> 6, tc = threadIdx.x & 63;
  const int r0v = threadIdx.x >> 4;          // 0..15 (row base for vec loads)
  const int c4  = (threadIdx.x & 15) * 4;    // column quad
  const int bid = blockIdx.x;

  if (bid >= 2560){
    const int sub = bid - 2560;              // 0..79
    if (sub == 0){
      for (int i = threadIdx.x; i < 1024; i += 256) SQ[i] = make_float2(0.f, 0.f);
    }
    const int bx = sub >> 2, oy = sub & 3;
    const float* Ws; int K; size_t dst; int kt;
    if (bx < 4)       { Ws = m2W; K = 256; dst = 0;      kt = bx; }
    else if (bx < 12) { Ws = p1W; K = 512; dst = 65536;  kt = bx - 4; }
    else if (bx < 16) { Ws = p2W; K = 256; dst = 196608; kt = bx - 12; }
    else              { Ws = kW;  K = 256; dst = 262144; kt = bx - 16; }
    const int k0 = kt*64, o0 = oy*64;
    #pragma unroll
    for (int q = 0; q < 4; ++q){
      int kr = q*16 + r0v;
      f32x4 v = *(const f32x4*)&Ws[(size_t)(k0+kr)*256 + o0 + c4];
      tile[kr][c4]   = v[0]; tile[kr][c4+1] = v[1];
      tile[kr][c4+2] = v[2]; tile[kr][c4+3] = v[3];
    }
    __syncthreads();
    #pragma unroll
    for (int q = 0; q < 16; ++q){
      int orow = q*4 + tr;
      WTs[dst + (size_t)(o0+orow)*K + k0 + tc] = f2bf(tile[tc][orow]);
    }
    return;
  }

  int i, jc;
  tri_decode(bid >> 2, i, jc);
  const int j0 = jc * 64;
  const int o0 = (bid & 3) * 64;
  #pragma unroll
  for (int q = 0; q < 4; ++q){
    int kr = q*16 + r0v;
    f32x4 v  = *(const f32x4*)&W[(size_t)(i*256 + j0 + kr)*256 + o0 + c4];   // W[(i,j)][o]
    f32x4 v2 = *(const f32x4*)&W[(size_t)((j0 + kr)*256 + i)*256 + o0 + c4]; // W[(j,i)][o]
    tile [kr][c4]   = v[0];  tile [kr][c4+1] = v[1];
    tile [kr][c4+2] = v[2];  tile [kr][c4+3] = v[3];
    tile2[kr][c4]   = v2[0]; tile2[kr][c4+1] = v2[1];
    tile2[kr][c4+2] = v2[2]; tile2[kr][c4+3] = v2[3];
  }
  __syncthreads();
  #pragma unroll
  for (int q = 0; q < 16; ++q){
    int orow = q*4 + tr;
    int j = j0 + tc;
    float v = (j < i) ? (tile[tc][orow] + tile2[tc][orow])
            : (j == i) ? tile[tc][orow] : 0.f;
    WTf[(size_t)(o0+orow)*65536 + (size_t)i*256 + j0 + tc] = f2bf(v);
  }
}

// ---------------------------------------------------------------------------
// k_corr2: one block per bt; lower-triangle only; per-wave 16x264 LDS row
// tile for coalesced fc stores. (R10 verified)
// ---------------------------------------------------------------------------
__global__ __launch_bounds__(256) void k_corr2(const float* __restrict__ x,
                                               unsigned short* __restrict__ fc){
  __shared__ unsigned short yT[256*72];
  __shared__ float rs[256];
  __shared__ unsigned short twbuf[4][16*264];
  const int bt = blockIdx.x;
  const float* xb = x + (size_t)bt * 16384;
  const int i = threadIdx.x;

  float sum = 0.f;
  #pragma unroll 8
  for (int s = 0; s < 64; ++s) sum += xb[s*256 + i];
  const float mean = sum * (1.f/64.f);

  float ss = 0.f;
  unsigned int* yT32 = (unsigned int*)yT;
  #pragma unroll 4
  for (int s = 0; s < 64; s += 2){
    float v0 = xb[s*256 + i] - mean;
    float v1 = xb[(s+1)*256 + i] - mean;
    unsigned short b0 = f2bf(v0), b1 = f2bf(v1);
    float r0 = bf2f(b0), r1 = bf2f(b1);
    ss += r0*r0 + r1*r1;
    yT32[(i*72 + s) >> 1] = (unsigned)b0 | ((unsigned)b1 << 16);
  }
  rs[i] = rsqrtf(ss);
  __syncthreads();

  const int w   = threadIdx.x >> 6;
  const int l   = threadIdx.x & 63;
  const int l15 = l & 15, lg = l >> 4;
  const int rtiles[4] = {2*w, 2*w + 1, 14 - 2*w, 15 - 2*w};
  unsigned short* tw = twbuf[w];

  for (int q = 0; q < 4; ++q){
    const int rt = rtiles[q];
    const int band = rt >> 2;
    const int ccmax = 2*band + 1;

    short8 RF[2];
    #pragma unroll
    for (int ks = 0; ks < 2; ++ks)
      RF[ks] = *(const short8*)&yT[(rt*16 + l15)*72 + ks*32 + lg*8];
    float rrow[4];
    #pragma unroll
    for (int r = 0; r < 4; ++r) rrow[r] = rs[rt*16 + lg*4 + r];

    for (int cc = 0; cc <= ccmax; ++cc){
      short8 CF[2][2];
      #pragma unroll
      for (int ct = 0; ct < 2; ++ct){
        int col = cc*32 + ct*16 + l15;
        #pragma unroll
        for (int ks = 0; ks < 2; ++ks)
          CF[ct][ks] = *(const short8*)&yT[col*72 + ks*32 + lg*8];
      }
      f32x4 acc[2];
      #pragma unroll
      for (int ct = 0; ct < 2; ++ct) acc[ct] = (f32x4){0.f,0.f,0.f,0.f};
      #pragma unroll
      for (int ks = 0; ks < 2; ++ks)
        #pragma unroll
        for (int ct = 0; ct < 2; ++ct)
          acc[ct] = __builtin_amdgcn_mfma_f32_16x16x32_bf16(
              RF[ks], CF[ct][ks], acc[ct], 0, 0, 0);
      float rc[2] = { rs[cc*32 + l15], rs[cc*32 + 16 + l15] };
      #pragma unroll
      for (int ct = 0; ct < 2; ++ct)
        #pragma unroll
        for (int r = 0; r < 4; ++r){
          float v = acc[ct][r] * rrow[r] * rc[ct];
          v = fminf(fmaxf(v, -1.f), 1.f);
          tw[(lg*4 + r)*264 + cc*32 + ct*16 + l15] = f2bf(v);
        }
    }
    // coalesced store: 16 rows x nc cols (DS in-order per wave; no barrier)
    const int nc  = (ccmax + 1) * 32;
    const int spr = nc >> 3;               // 8-elem slots per row
    const int total = spr << 4;            // 16 rows
    for (int s = l; s < total; s += 64){
      int r  = s / spr;
      int co = (s - r*spr) * 8;
      short8 v = *(const short8*)&tw[r*264 + co];
      *(short8*)&fc[(size_t)bt*65536 + (size_t)(rt*16 + r)*256 + co] = v;
    }
  }
}

// ---------------------------------------------------------------------------
// k_gemm: triangle-folded GEMM, 2-phase double-buffered LDS (48KB, 3/CU).
// grid 640 = 40 k-groups x 16 (m,n); BM=64, BN=128, BK=64; XCD swizzle.
// P partials bf16. (R13 verified — restored after R14 regression)
// ---------------------------------------------------------------------------
__global__ __launch_bounds__(256) void k_gemm(const unsigned short* __restrict__ fc,
                                              const unsigned short* __restrict__ WTf,
                                              unsigned short* __restrict__ P){
  __shared__ unsigned short Al[2][64*64];
  __shared__ unsigned short Bl[2][128*64];
  const int bid  = blockIdx.x;
  const int wgid = (bid & 7)*80 + (bid >> 3);   // bijective (640 % 8 == 0)
  const int g    = wgid >> 4;
  const int rem  = wgid & 15;
  const int n0   = (rem >> 3) * 128;
  const int m0   = (rem & 7) * 64;
  const int t    = threadIdx.x;
  const int w = t >> 6, l = t & 63, l15 = l & 15, lg = l >> 4;
  const int wr = (w >> 1) * 32;
  const int wc = (w & 1) * 64;

  auto stage = [&](int bsel, int s2){
    int ti, tjc;
    tri_decode(g*16 + s2, ti, tjc);
    const int kk = ti*256 + tjc*64;
    #pragma unroll
    for (int i2 = 0; i2 < 2; ++i2){
      int c = i2*256 + t;
      int row = c >> 3, ch = c & 7;
      int sch = ch ^ (row & 7);
      gload_lds16(fc + (size_t)(m0+row)*65536 + kk + sch*8, &Al[bsel][c*8]);
    }
    #pragma unroll
    for (int i2 = 0; i2 < 4; ++i2){
      int c = i2*256 + t;
      int row = c >> 3, ch = c & 7;
      int sch = ch ^ (row & 7);
      gload_lds16(WTf + (size_t)(n0+row)*65536 + kk + sch*8, &Bl[bsel][c*8]);
    }
  };

  f32x4 acc[2][4];
  #pragma unroll
  for (int a = 0; a < 2; ++a)
    #pragma unroll
    for (int b = 0; b < 4; ++b) acc[a][b] = (f32x4){0.f,0.f,0.f,0.f};

  stage(0, 0);
  int cur = 0;
  for (int s2 = 0; s2 < 16; ++s2){
    __syncthreads();                  // buf[cur] staged (vmcnt drained)
    if (s2 < 15) stage(cur ^ 1, s2 + 1);   // next-tile loads fly under compute
    #pragma unroll
    for (int ks = 0; ks < 2; ++ks){
      short8 af[2], bf[4];
      #pragma unroll
      for (int rt = 0; rt < 2; ++rt){
        int row = wr + rt*16 + l15;
        int pch = (ks*4 + lg) ^ (row & 7);
        af[rt] = *(const short8*)&Al[cur][row*64 + pch*8];
      }
      #pragma unroll
      for (int ct = 0; ct < 4; ++ct){
        int row = wc + ct*16 + l15;
        int pch = (ks*4 + lg) ^ (row & 7);
        bf[ct] = *(const short8*)&Bl[cur][row*64 + pch*8];
      }
      #pragma unroll
      for (int rt = 0; rt < 2; ++rt)
        #pragma unroll
        for (int ct = 0; ct < 4; ++ct)
          acc[rt][ct] = __builtin_amdgcn_mfma_f32_16x16x32_bf16(
              af[rt], bf[ct], acc[rt][ct], 0, 0, 0);
    }
    cur ^= 1;
  }

  unsigned short* Pb = P + (size_t)g * 131072;
  #pragma unroll
  for (int rt = 0; rt < 2; ++rt)
    #pragma unroll
    for (int ct = 0; ct < 4; ++ct)
      #pragma unroll
      for (int r = 0; r < 4; ++r){
        int row = m0 + wr + rt*16 + lg*4 + r;
        int col = n0 + wc + ct*16 + l15;
        Pb[(size_t)row*256 + col] = f2bf(acc[rt][ct][r]);
      }
}

// ---------------------------------------------------------------------------
// k_reduce: z1 = sum_{g<40} bf16 P[g]. R15: 128 blocks x 4 rows (1 wave/row),
// 8B loads, f32x4 z-store, LDS cross-wave stats -> 1 atomic pair/col/block.
// ---------------------------------------------------------------------------
__global__ __launch_bounds__(256) void k_reduce(const unsigned short* __restrict__ P,
                                                float* __restrict__ z,
                                                float2* __restrict__ SQ1){
  __shared__ float2 sq4[4][256];
  const int t  = threadIdx.x;
  const int wv = t >> 6;                 // wave = row within block
  const int row = blockIdx.x*4 + wv;
  const int c4  = (t & 63) * 4;
  float s0 = 0.f, s1 = 0.f, s2 = 0.f, s3 = 0.f;
  #pragma unroll 8
  for (int ks = 0; ks < 40; ++ks){
    const unsigned* p = (const unsigned*)&P[(size_t)ks*131072 + row*256 + c4];
    unsigned u0 = p[0], u1 = p[1];
    s0 += bf2f((unsigned short)(u0 & 0xffffu));
    s1 += bf2f((unsigned short)(u0 >> 16));
    s2 += bf2f((unsigned short)(u1 & 0xffffu));
    s3 += bf2f((unsigned short)(u1 >> 16));
  }
  *(f32x4*)&z[row*256 + c4] = (f32x4){s0, s1, s2, s3};
  sq4[wv][c4]     = make_float2(s0, s0*s0);
  sq4[wv][c4 + 1] = make_float2(s1, s1*s1);
  sq4[wv][c4 + 2] = make_float2(s2, s2*s2);
  sq4[wv][c4 + 3] = make_float2(s3, s3*s3);
  __syncthreads();
  float S = sq4[0][t].x + sq4[1][t].x + sq4[2][t].x + sq4[3][t].x;
  float Q = sq4[0][t].y + sq4[1][t].y + sq4[2][t].y + sq4[3][t].y;
  atomicAdd(&SQ1[t].x, S);
  atomicAdd(&SQ1[t].y, Q);
}

// ---------------------------------------------------------------------------
// k_sgm: weight-stationary MFMA layer. 16 rows x 64 cols per block,
// grid (32,4) = 128 blocks. (R10 verified)
// ---------------------------------------------------------------------------
template<int KK, int NC64, bool CAT>
__global__ __launch_bounds__(256) void k_sgm(const float* __restrict__ zin,
                                             const float* __restrict__ es,
                                             const unsigned short* __restrict__ WTl_g,
                                             const float2* __restrict__ SQin,
                                             const float* __restrict__ g,
                                             const float* __restrict__ be,
                                             float2* __restrict__ SQout,
                                             float* __restrict__ zout){
  constexpr int NCOLS = NC64 * 64;
  constexpr int NP = KK / 64;
  __shared__ unsigned short Bl[NP][NCOLS*64];
  __shared__ float2 ssl[256];
  const int r0 = blockIdx.x * 16;
  const int n0 = blockIdx.y * NCOLS;
  const int b  = r0 >> 6;
  const int t = threadIdx.x;
  const int l = t & 63, l15 = l & 15, lg = (l >> 4) & 3;
  const int w = t >> 6;
  const int wc = w * (NCOLS/4);

  #pragma unroll
  for (int p = 0; p < NP; ++p){
    #pragma unroll
    for (int i = 0; i < NCOLS*8/256; ++i){
      int c = i*256 + t;
      int row = c >> 3, ch = c & 7;
      int sch = ch ^ (row & 7);
      gload_lds16(WTl_g + (size_t)(n0+row)*KK + p*64 + sch*8, &Bl[p][c*8]);
    }
  }
  {
    float2 sq = SQin[t];
    float mu  = sq.x * (1.f/512.f);
    float var = sq.y * (1.f/512.f) - mu*mu;
    float sc  = g[t] * rsqrtf(var + 1e-5f);
    ssl[t] = make_float2(sc, be[t] - mu*sc);
  }
  __syncthreads();

  short8 a[KK/32];
  #pragma unroll
  for (int ks = 0; ks < KK/32; ++ks){
    int k = ks*32 + lg*8;
    short8 v;
    if (!CAT || k < 256){
      f32x4 lo = *(const f32x4*)&zin[(size_t)(r0+l15)*256 + k];
      f32x4 hi = *(const f32x4*)&zin[(size_t)(r0+l15)*256 + k + 4];
      #pragma unroll
      for (int j = 0; j < 4; ++j){
        float2 sv0 = ssl[k+j];
        float2 sv1 = ssl[k+4+j];
        v[j]   = (short)f2bf(fmaxf(lo[j]*sv0.x + sv0.y, 0.f));
        v[4+j] = (short)f2bf(fmaxf(hi[j]*sv1.x + sv1.y, 0.f));
      }
    } else {
      f32x4 lo = *(const f32x4*)&es[b*256 + (k-256)];
      f32x4 hi = *(const f32x4*)&es[b*256 + (k-256) + 4];
      #pragma unroll
      for (int j = 0; j < 4; ++j){
        v[j]   = (short)f2bf(lo[j]);
        v[4+j] = (short)f2bf(hi[j]);
      }
    }
    a[ks] = v;
  }

  f32x4 acc[NC64];
  #pragma unroll
  for (int ct = 0; ct < NC64; ++ct) acc[ct] = (f32x4){0.f,0.f,0.f,0.f};
  #pragma unroll
  for (int ks = 0; ks < KK/32; ++ks){
    int p = ks >> 1;
    int kin = (ks & 1) * 4;
    #pragma unroll
    for (int ct = 0; ct < NC64; ++ct){
      int row = wc + ct*16 + l15;
      int pch = (kin + lg) ^ (row & 7);
      short8 bfr = *(const short8*)&Bl[p][row*64 + pch*8];
      acc[ct] = __builtin_amdgcn_mfma_f32_16x16x32_bf16(a[ks], bfr, acc[ct], 0, 0, 0);
    }
  }

  #pragma unroll
  for (int ct = 0; ct < NC64; ++ct){
    int col = n0 + wc + ct*16 + l15;
    #pragma unroll
    for (int r = 0; r < 4; ++r)
      zout[(size_t)(r0 + lg*4 + r)*256 + col] = acc[ct][r];
    float S = acc[ct][0] + acc[ct][1] + acc[ct][2] + acc[ct][3];
    float Q = acc[ct][0]*acc[ct][0] + acc[ct][1]*acc[ct][1]
            + acc[ct][2]*acc[ct][2] + acc[ct][3]*acc[ct][3];
    S += __shfl_xor(S, 16); S += __shfl_xor(S, 32);
    Q += __shfl_xor(Q, 16); Q += __shfl_xor(Q, 32);
    if ((l >> 4) == 0){
      atomicAdd(&SQout[col].x, S);
      atomicAdd(&SQout[col].y, Q);
    }
  }
}

// ---------------------------------------------------------------------------
// k_qmean2: 32 blocks = (8 b) x (4 col-quarters). (R10 verified)
// ---------------------------------------------------------------------------
__global__ __launch_bounds__(256) void k_qmean2(const float* __restrict__ z4,
                                                const float2* __restrict__ SQ4,
                                                const float* __restrict__ g,
                                                const float* __restrict__ be,
                                                const float* __restrict__ qW,
                                                const float* __restrict__ qb,
                                                float* __restrict__ q){
  __shared__ float qWl[256*64];    // 64KB: qW[:, n0..n0+64) packed [k][c]
  __shared__ float hm[256];
  __shared__ float part[4][64];
  const int b  = blockIdx.x & 7;
  const int n0 = (blockIdx.x >> 3) * 64;
  const int t  = threadIdx.x;

  #pragma unroll
  for (int it = 0; it < 16; ++it){
    int s4 = it*256 + t;           // 16B-slot index
    int k  = s4 >> 4;
    int c  = (s4 & 15) * 4;
    gload_lds16(qW + (size_t)k*256 + n0 + c, (char*)qWl + (size_t)s4*16);
  }
  {
    float2 sq = SQ4[t];
    float mu  = sq.x * (1.f/512.f);
    float var = sq.y * (1.f/512.f) - mu*mu;
    float sc  = g[t] * rsqrtf(var + 1e-5f);
    float sh  = be[t] - mu*sc;
    float s = 0.f;
    #pragma unroll 8
    for (int tt = 0; tt < 64; ++tt)
      s += fmaxf(z4[(size_t)((b<<6)+tt)*256 + t]*sc + sh, 0.f);
    hm[t] = s * (1.f/64.f);
  }
  __syncthreads();                 // drains qW gloads + hm visible

  const int col = t & 63, kq = t >> 6;
  float a = 0.f;
  #pragma unroll 8
  for (int k2 = 0; k2 < 64; ++k2){
    int k = kq*64 + k2;
    a += hm[k] * qWl[k*64 + col];
  }
  part[kq][col] = a;
  __syncthreads();
  if (t < 64)
    q[b*256 + n0 + t] = part[0][t] + part[1][t] + part[2][t] + part[3][t] + qb[n0 + t];
}

// ---------------------------------------------------------------------------
// k_att2: 16 rows/block; Hh = relu(bn4(z4)); kvec = Hh@kW + kb;
// s = dot(q_b,kvec)/16; out = Hh*sigmoid(s). (R7-R13 verified)
// ---------------------------------------------------------------------------
__global__ __launch_bounds__(256) void k_att2(const float* __restrict__ z4,
                                              const float2* __restrict__ SQ4,
                                              const float* __restrict__ g,
                                              const float* __restrict__ be,
                                              const unsigned short* __restrict__ kWT,
                                              const float* __restrict__ kb,
                                              const float* __restrict__ qv,
                                              float* __restrict__ out){
  __shared__ unsigned short Bl[4][256*64];
  __shared__ float2 ssl[256];
  __shared__ float Hh[16][260];
  __shared__ float pr[4][16];
  __shared__ float sig[16];
  const int r0 = blockIdx.x * 16;
  const int b  = r0 >> 6;
  const int t = threadIdx.x;
  const int l = t & 63, l15 = l & 15, lg = (l >> 4) & 3;
  const int w = t >> 6;
  const int wc = w * 64;

  #pragma unroll
  for (int p = 0; p < 4; ++p){
    #pragma unroll
    for (int i = 0; i < 8; ++i){
      int c = i*256 + t;
      int row = c >> 3, ch = c & 7;
      int sch = ch ^ (row & 7);
      gload_lds16(kWT + (size_t)row*256 + p*64 + sch*8, &Bl[p][c*8]);
    }
  }
  {
    float2 sq = SQ4[t];
    float mu  = sq.x * (1.f/512.f);
    float var = sq.y * (1.f/512.f) - mu*mu;
    float sc  = g[t] * rsqrtf(var + 1e-5f);
    ssl[t] = make_float2(sc, be[t] - mu*sc);
  }
  __syncthreads();

  short8 a[8];
  #pragma unroll
  for (int ks = 0; ks < 8; ++ks){
    int k = ks*32 + lg*8;
    f32x4 lo = *(const f32x4*)&z4[(size_t)(r0+l15)*256 + k];
    f32x4 hi = *(const f32x4*)&z4[(size_t)(r0+l15)*256 + k + 4];
    short8 v;
    f32x4 h0, h1;
    #pragma unroll
    for (int j = 0; j < 4; ++j){
      float2 sv0 = ssl[k+j];
      float2 sv1 = ssl[k+4+j];
      float x0 = fmaxf(lo[j]*sv0.x + sv0.y, 0.f);
      float x1 = fmaxf(hi[j]*sv1.x + sv1.y, 0.f);
      h0[j] = x0; h1[j] = x1;
      v[j]   = (short)f2bf(x0);
      v[4+j] = (short)f2bf(x1);
    }
    a[ks] = v;
    *(f32x4*)&Hh[l15][k]     = h0;
    *(f32x4*)&Hh[l15][k + 4] = h1;
  }

  f32x4 acc[4];
  #pragma unroll
  for (int ct = 0; ct < 4; ++ct) acc[ct] = (f32x4){0.f,0.f,0.f,0.f};
  #pragma unroll
  for (int ks = 0; ks < 8; ++ks){
    int p = ks >> 1;
    int kin = (ks & 1) * 4;
    #pragma unroll
    for (int ct = 0; ct < 4; ++ct){
      int row = wc + ct*16 + l15;
      int pch = (kin + lg) ^ (row & 7);
      short8 bfr = *(const short8*)&Bl[p][row*64 + pch*8];
      acc[ct] = __builtin_amdgcn_mfma_f32_16x16x32_bf16(a[ks], bfr, acc[ct], 0, 0, 0);
    }
  }

  float p4[4] = {0.f, 0.f, 0.f, 0.f};
  #pragma unroll
  for (int ct = 0; ct < 4; ++ct){
    int col = wc + ct*16 + l15;
    float qc  = qv[b*256 + col];
    float kbc = kb[col];
    #pragma unroll
    for (int r = 0; r < 4; ++r) p4[r] += (acc[ct][r] + kbc) * qc;
  }
  #pragma unroll
  for (int r = 0; r < 4; ++r){
    p4[r] += __shfl_xor(p4[r], 1);
    p4[r] += __shfl_xor(p4[r], 2);
    p4[r] += __shfl_xor(p4[r], 4);
    p4[r] += __shfl_xor(p4[r], 8);
  }
  if (l15 == 0){
    #pragma unroll
    for (int r = 0; r < 4; ++r) pr[w][lg*4 + r] = p4[r];
  }
  __syncthreads();
  if (t < 16){
    float s = pr[0][t] + pr[1][t] + pr[2][t] + pr[3][t];
    sig[t] = 1.f / (1.f + __expf(-s * (1.f/16.f)));
  }
  __syncthreads();
  #pragma unroll
  for (int r = 0; r < 16; ++r)
    out[(size_t)(r0+r)*256 + t] = Hh[r][t] * sig[r];
}

// ---------------------------------------------------------------------------
extern "C" void kernel_launch(void* const* d_in, const int* in_sizes, int n_in,
                              void* d_out, int out_size, void* d_ws, size_t ws_size,
                              hipStream_t stream){
  (void)in_sizes; (void)n_in; (void)out_size; (void)ws_size;
  const float* x    = (const float*)d_in[0];
  const float* e_s  = (const float*)d_in[1];
  const float* qW   = (const float*)d_in[2];
  const float* qb   = (const float*)d_in[3];
  const float* kW   = (const float*)d_in[4];
  const float* kb   = (const float*)d_in[5];
  const float* m1W  = (const float*)d_in[6];
  const float* m1g  = (const float*)d_in[8];
  const float* m1be = (const float*)d_in[9];
  const float* m2W  = (const float*)d_in[10];
  const float* m2g  = (const float*)d_in[12];
  const float* m2be = (const float*)d_in[13];
  const float* p1W  = (const float*)d_in[14];
  const float* p1g  = (const float*)d_in[16];
  const float* p1be = (const float*)d_in[17];
  const float* p2W  = (const float*)d_in[18];
  const float* p2g  = (const float*)d_in[20];
  const float* p2be = (const float*)d_in[21];
  // biases m1b,m2b,p1b,p2b cancel in BN — unused.

  char* ws = (char*)d_ws;
  unsigned short* WTf = (unsigned short*)ws; ws += 33554432;
  unsigned short* fc  = (unsigned short*)ws; ws += 67108864;
  unsigned short* P   = (unsigned short*)ws; ws += 16777216;  // 10.5MB used (bf16, 40 groups)
  float* z1           = (float*)ws;  ws += 524288;
  float* z2           = (float*)ws;  ws += 524288;
  float* z3           = (float*)ws;  ws += 524288;
  float* z4           = (float*)ws;  ws += 524288;
  unsigned short* WTs = (unsigned short*)ws; ws += 655360;
  float2* SQ          = (float2*)ws; ws += 8192;   // SQ1..SQ4, 256 each
  float* qvv          = (float*)ws;  ws += 8192;
  float* out = (float*)d_out;

  const unsigned short* m2WT = WTs;
  const unsigned short* p1WT = WTs + 65536;
  const unsigned short* p2WT = WTs + 196608;
  const unsigned short* kWT  = WTs + 262144;
  float2* SQ1 = SQ, *SQ2 = SQ + 256, *SQ3 = SQ + 512, *SQ4 = SQ + 768;

  k_wtf   <<<2640, 256, 0, stream>>>(m1W, WTf, m2W, p1W, p2W, kW, WTs, SQ);
  k_corr2 <<<512, 256, 0, stream>>>(x, fc);
  k_gemm  <<<640, 256, 0, stream>>>(fc, WTf, P);
  k_reduce<<<128, 256, 0, stream>>>(P, z1, SQ1);
  k_sgm<256,1,false><<<dim3(32,4), 256, 0, stream>>>(z1, nullptr, m2WT, SQ1, m1g, m1be, SQ2, z2);
  k_sgm<512,1,true> <<<dim3(32,4), 256, 0, stream>>>(z2, e_s, p1WT, SQ2, m2g, m2be, SQ3, z3);
  k_sgm<256,1,false><<<dim3(32,4), 256, 0, stream>>>(z3, nullptr, p2WT, SQ3, p1g, p1be, SQ4, z4);
  k_qmean2<<<32, 256, 0, stream>>>(z4, SQ4, p2g, p2be, qW, qb, qvv);
  k_att2  <<<32, 256, 0, stream>>>(z4, SQ4, p2g, p2be, kWT, kb, qvv, out);
}